// Round 1
// baseline (88.129 us; speedup 1.0000x reference)
//
#include <hip/hip_runtime.h>
#include <stdint.h>

#define T_DIM 4096
#define B_DIM 4
#define C_DIM 64
#define S_DIM (B_DIM * T_DIM)   // 16384 positions
#define L_DIM 15
#define N_NODE 64
#define EPSF 1e-12f

typedef __attribute__((ext_vector_type(8))) short  short8v;   // 8 x bf16 bits (4 VGPRs)
typedef __attribute__((ext_vector_type(4))) float  float4v;   // 4 x f32

// round-half-up float -> bf16 bits (cheap; error <= 0.5 ulp + tiny bias)
__device__ __forceinline__ unsigned short f2bf(float f) {
    return (unsigned short)((__builtin_bit_cast(uint32_t, f) + 0x8000u) >> 16);
}
// proper RNE for the one-time weight conversion
__device__ __forceinline__ unsigned short f2bf_rne(float f) {
    uint32_t u = __builtin_bit_cast(uint32_t, f);
    return (unsigned short)((u + 0x7fffu + ((u >> 16) & 1u)) >> 16);
}

// ---------------------------------------------------------------------------
// K0: conv_w [k=4096][n=64] fp32  ->  w2t [n=64][k=4096] bf16 (B-frag friendly)
// ---------------------------------------------------------------------------
__global__ void k_convert_w(const float* __restrict__ conv_w,
                            unsigned short* __restrict__ w2t) {
    int i = blockIdx.x * 256 + threadIdx.x;     // i = n*4096 + k
    if (i < C_DIM * C_DIM * N_NODE) {
        int n = i >> 12;
        int k = i & 4095;
        w2t[i] = f2bf_rne(conv_w[(size_t)k * N_NODE + n]);
    }
}

// ---------------------------------------------------------------------------
// K1b: D[s][j] = (x_s . x_{s+j})^2 for j=0..14 (0 when crossing batch end)
// one wave per position s; lane = channel c
// ---------------------------------------------------------------------------
__global__ void k_dots(const float* __restrict__ x, float* __restrict__ D) {
    int wv = threadIdx.x >> 6, lane = threadIdx.x & 63;
    int s = blockIdx.x * 4 + wv;
    int t = s & (T_DIM - 1);
    float xv = x[(size_t)s * C_DIM + lane];
    #pragma unroll
    for (int j = 0; j < L_DIM; ++j) {
        float y = 0.f;
        if (t + j < T_DIM) y = x[(size_t)(s + j) * C_DIM + lane];
        float p = xv * y;
        #pragma unroll
        for (int off = 32; off; off >>= 1) p += __shfl_xor(p, off);
        if (lane == 0) D[(size_t)s * L_DIM + j] = p * p;
    }
}

// ---------------------------------------------------------------------------
// K1: g_part[split][s][n] = sum over c-range of  x[s,c]*x[s,d] * W[c*64+d, n]
// GEMM M=16384 K=4096 N=64 via mfma_f32_16x16x32_bf16, F generated on the fly.
// BM=64 rows/block, 4 waves (wave = 16 rows x 64 cols), 2-way K-split.
// ---------------------------------------------------------------------------
__global__ __launch_bounds__(256) void k_gemm(const float* __restrict__ x,
                                              const unsigned short* __restrict__ w2t,
                                              float* __restrict__ g) {
    __shared__ float xs[64][68];           // +4 pad: 2-way banks (free), keeps 16B align
    __shared__ unsigned short wl[64][72];  // +8 pad: 2-way banks, 16B align

    int tid = threadIdx.x;
    int split = blockIdx.x & 1;
    int m0 = (blockIdx.x >> 1) * 64;

    // stage x tile (64 rows x 64 ch fp32)
    for (int i = tid; i < 1024; i += 256) {
        int row = i >> 4, c4 = (i & 15) * 4;
        *(float4v*)&xs[row][c4] =
            *(const float4v*)(x + (size_t)(m0 + row) * C_DIM + c4);
    }

    int lane = tid & 63, wv = tid >> 6;
    int arow = wv * 16 + (lane & 15);      // this lane's output row within block
    int kgrp = (lane >> 4) * 8;            // k-offset of this lane's 8 frag elems
    const float* xrow = xs[arow];

    float4v acc[4];
    #pragma unroll
    for (int nt = 0; nt < 4; ++nt) acc[nt] = (float4v){0.f, 0.f, 0.f, 0.f};

    int c0 = split * 32;
    for (int ci = 0; ci < 32; ++ci) {
        int c = c0 + ci;
        __syncthreads();
        // stage W chunk: k = c*64 + (0..63), all 64 n  (8 KB bf16)
        for (int i = tid; i < 512; i += 256) {
            int n = i >> 3, kk = (i & 7) * 8;
            *(short8v*)&wl[n][kk] =
                *(const short8v*)(w2t + ((size_t)n << 12) + (c << 6) + kk);
        }
        __syncthreads();

        float xc = xrow[c];
        #pragma unroll
        for (int h = 0; h < 2; ++h) {
            int db = h * 32 + kgrp;        // d-offset == k_local within the 64-chunk
            float4v p0 = *(const float4v*)&xrow[db];
            float4v p1 = *(const float4v*)&xrow[db + 4];
            short8v a;
            a[0] = (short)f2bf(xc * p0[0]);
            a[1] = (short)f2bf(xc * p0[1]);
            a[2] = (short)f2bf(xc * p0[2]);
            a[3] = (short)f2bf(xc * p0[3]);
            a[4] = (short)f2bf(xc * p1[0]);
            a[5] = (short)f2bf(xc * p1[1]);
            a[6] = (short)f2bf(xc * p1[2]);
            a[7] = (short)f2bf(xc * p1[3]);
            #pragma unroll
            for (int nt = 0; nt < 4; ++nt) {
                short8v bfr = *(const short8v*)&wl[nt * 16 + (lane & 15)][db];
                acc[nt] = __builtin_amdgcn_mfma_f32_16x16x32_bf16(a, bfr, acc[nt], 0, 0, 0);
            }
        }
    }

    // epilogue: C/D layout col = lane&15, row = (lane>>4)*4 + j  [HW-verified]
    float* gp = g + (size_t)split * ((size_t)S_DIM * N_NODE);
    int crow0 = m0 + wv * 16 + (lane >> 4) * 4;
    int col0 = lane & 15;
    #pragma unroll
    for (int nt = 0; nt < 4; ++nt)
        #pragma unroll
        for (int j = 0; j < 4; ++j)
            gp[(size_t)(crow0 + j) * N_NODE + nt * 16 + col0] = acc[nt][j];
}

// ---------------------------------------------------------------------------
// K2: out[b,t,n] = (sum_l w_l * g[b,t+l-7,n]) * rsqrt(max(sq,eps)) + conv_b[n]
//     sq = sum_{l,l'} w_l w_l' D[min(p,p')][|l-l'|]
// one 64-thread block per (b,t); lane = n
// ---------------------------------------------------------------------------
__global__ void k_final(const float* __restrict__ g, const float* __restrict__ D,
                        const float* __restrict__ w, const float* __restrict__ conv_b,
                        float* __restrict__ out) {
    int lane = threadIdx.x;                 // 0..63
    int bt = blockIdx.x;
    int b = bt >> 12, t = bt & (T_DIM - 1);
    const float* D_b = D + (size_t)b * T_DIM * L_DIM;

    float sq = 0.f;
    for (int idx = lane; idx < L_DIM * L_DIM; idx += 64) {
        int l = idx / 15, lp = idx % 15;
        int lmin = (l < lp) ? l : lp;
        int j = (l > lp) ? (l - lp) : (lp - l);
        int p = t + lmin - 7;
        if (p >= 0 && p < T_DIM)
            sq += w[l] * w[lp] * D_b[(size_t)p * L_DIM + j];
    }
    #pragma unroll
    for (int off = 32; off; off >>= 1) sq += __shfl_xor(sq, off);
    float rsq = rsqrtf(fmaxf(sq, EPSF));

    const float* g0 = g;
    const float* g1 = g + (size_t)S_DIM * N_NODE;
    float acc = 0.f;
    size_t base = ((size_t)b * T_DIM) * N_NODE + lane;
    #pragma unroll
    for (int l = 0; l < L_DIM; ++l) {
        int p = t + l - 7;
        if (p >= 0 && p < T_DIM) {
            size_t gi = base + (size_t)p * N_NODE;
            acc += w[l] * (g0[gi] + g1[gi]);
        }
    }
    out[(size_t)bt * N_NODE + lane] = acc * rsq + conv_b[lane];
}

// ---------------------------------------------------------------------------
extern "C" void kernel_launch(void* const* d_in, const int* in_sizes, int n_in,
                              void* d_out, int out_size, void* d_ws, size_t ws_size,
                              hipStream_t stream) {
    const float* x      = (const float*)d_in[0];
    const float* w      = (const float*)d_in[1];
    const float* conv_w = (const float*)d_in[2];
    const float* conv_b = (const float*)d_in[3];
    float* out = (float*)d_out;

    char* ws = (char*)d_ws;
    unsigned short* w2t = (unsigned short*)ws;                   //   524,288 B
    float* g            = (float*)(ws + 524288);                 // 2 x 4 MB (K-split partials)
    float* D            = (float*)(ws + 524288 + 2 * 4194304);   //   983,040 B

    hipLaunchKernelGGL(k_convert_w, dim3(1024), dim3(256), 0, stream, conv_w, w2t);
    hipLaunchKernelGGL(k_dots,      dim3(4096), dim3(256), 0, stream, x, D);
    hipLaunchKernelGGL(k_gemm,      dim3(512),  dim3(256), 0, stream, x, w2t, g);
    hipLaunchKernelGGL(k_final,     dim3(16384), dim3(64), 0, stream, g, D, w, conv_b, out);
}

// Round 3
// 61.217 us; speedup vs baseline: 1.4396x; 1.4396x over previous
//
#include <hip/hip_runtime.h>
#include <stdint.h>

#define T_DIM 4096
#define S_DIM 16384          // 4 batches x 4096
#define EPSF 1e-12f

typedef __attribute__((ext_vector_type(8))) short   short8v;
typedef __attribute__((ext_vector_type(4))) float   float4v;
typedef __attribute__((ext_vector_type(4))) uint32_t uint4v;

__device__ __forceinline__ unsigned short f2bf_rne(float f) {
    uint32_t u = __builtin_bit_cast(uint32_t, f);
    return (unsigned short)((u + 0x7fffu + ((u >> 16) & 1u)) >> 16);
}
__device__ __forceinline__ uint32_t cvtpk(float lo, float hi) {
    uint32_t r;
    asm("v_cvt_pk_bf16_f32 %0, %1, %2" : "=v"(r) : "v"(lo), "v"(hi));
    return r;
}

// ---------------------------------------------------------------------------
// K0: conv_w [k=4096][n=64] f32 -> bf16 fragment stream wfrag[cc][nt][h][ln]x16B
//     granule (cc,nt,h,ln) holds W[cc*64 + h*32 + (ln>>4)*8 + j][nt*16+(ln&15)]
// ---------------------------------------------------------------------------
__global__ __launch_bounds__(256) void k_convert(const float* __restrict__ conv_w,
                                                 unsigned short* __restrict__ wfrag) {
    __shared__ unsigned short lb[64][65];
    int tid = threadIdx.x;
    int cc  = blockIdx.x;                       // 0..63
    for (int i = tid; i < 4096; i += 256) {     // coalesced read of 16KB slab
        lb[i >> 6][i & 63] = f2bf_rne(conv_w[((size_t)cc << 12) + i]);
    }
    __syncthreads();
    for (int gi = tid; gi < 512; gi += 256) {
        int nt = gi >> 7, h = (gi >> 6) & 1, ln = gi & 63;
        int n  = (nt << 4) + (ln & 15);
        int kb = (h << 5) + ((ln >> 4) << 3);
        uint4v u;
        #pragma unroll
        for (int q = 0; q < 4; ++q)
            u[q] = (uint32_t)lb[kb + 2 * q][n] | ((uint32_t)lb[kb + 2 * q + 1][n] << 16);
        *(uint4v*)(wfrag + ((size_t)cc << 12) + (gi << 3)) = u;
    }
}

// ---------------------------------------------------------------------------
// K1: dots + norm partials.  Block = 64 positions (lane = position).
//  acc_j = x_s . x_{s+j}  (zero-padded past batch end), dsq = acc_j^2
//  P[l][s] = w_l*dsq[s][0] + sum_{j=1..14-l} 2*w_{l+j}*dsq[s][j]
// ---------------------------------------------------------------------------
__global__ __launch_bounds__(256) void k_dotsP(const float* __restrict__ x,
                                               const float* __restrict__ w,
                                               float* __restrict__ P) {
    __shared__ float xt[78 * 65];       // pitch 65, rows s0..s0+77
    __shared__ float pd[4][64][17];
    __shared__ float dsq[64][17];
    int tid = threadIdx.x, lane = tid & 63, wv = tid >> 6;
    int s0 = blockIdx.x << 6;
    int bt0 = s0 & (T_DIM - 1);
    for (int i = tid; i < 78 * 16; i += 256) {
        int r = i >> 4, c4 = (i & 15) << 2;
        float4v v = {0.f, 0.f, 0.f, 0.f};
        if (bt0 + r < T_DIM) v = *(const float4v*)(x + (((size_t)(s0 + r)) << 6) + c4);
        #pragma unroll
        for (int q = 0; q < 4; ++q) xt[r * 65 + c4 + q] = v[q];
    }
    __syncthreads();
    float acc[15];
    #pragma unroll
    for (int j = 0; j < 15; ++j) acc[j] = 0.f;
    int c0 = wv << 4;
    for (int c = c0; c < c0 + 16; ++c) {
        const float* base = &xt[lane * 65 + c];
        float xl = base[0];
        #pragma unroll
        for (int j = 0; j < 15; ++j) acc[j] += xl * base[j * 65];
    }
    #pragma unroll
    for (int j = 0; j < 15; ++j) pd[wv][lane][j] = acc[j];
    __syncthreads();
    for (int i = tid; i < 960; i += 256) {      // i = j*64 + s
        int s = i & 63, j = i >> 6;
        float d = pd[0][s][j] + pd[1][s][j] + pd[2][s][j] + pd[3][s][j];
        dsq[s][j] = d * d;
    }
    __syncthreads();
    for (int i = tid; i < 960; i += 256) {      // i = l*64 + s  (coalesced P writes)
        int s = i & 63, l = i >> 6;
        float sum = w[l] * dsq[s][0];
        for (int j = 1; j <= 14 - l; ++j) sum += 2.f * w[l + j] * dsq[s][j];
        P[(size_t)l * S_DIM + s0 + s] = sum;
    }
}

// ---------------------------------------------------------------------------
// K2: rsq[s] = rsqrt(max(sum_l w_l * P[l][s+l-7], eps))
// ---------------------------------------------------------------------------
__global__ __launch_bounds__(256) void k_rsq(const float* __restrict__ P,
                                             const float* __restrict__ w,
                                             float* __restrict__ rsq) {
    int s = blockIdx.x * 256 + threadIdx.x;
    int t = s & (T_DIM - 1);
    float sum = 0.f;
    #pragma unroll
    for (int l = 0; l < 15; ++l) {
        int tp = t + l - 7;
        if (0 <= tp && tp < T_DIM) sum += w[l] * P[(size_t)l * S_DIM + s + l - 7];
    }
    rsq[s] = rsqrtf(fmaxf(sum, EPSF));
}

// ---------------------------------------------------------------------------
// K3: GEMM  g_part[split][s][n] (M=16384, K=4096, N=64), F generated on the fly.
// NO LDS, NO barriers: each lane loads its 8 B-fragment granules directly from
// the fragment stream (coalesced dwordx4, L1-resident chunk). Compiler
// software-pipelines loads under MFMAs freely.
// ---------------------------------------------------------------------------
__global__ __launch_bounds__(256) void k_gemm(const float* __restrict__ x,
                                              const unsigned short* __restrict__ wfrag,
                                              float* __restrict__ g) {
    int tid = threadIdx.x, lane = tid & 63, wv = tid >> 6;
    int split = blockIdx.x & 1;
    int m0 = (blockIdx.x >> 1) << 6;
    int c0 = split << 5;

    int prow = (wv << 4) + (lane & 15);
    int kgrp = (lane >> 4) << 3;
    const float* xr = x + (((size_t)(m0 + prow)) << 6);
    // A-operand registers: d-halves (fixed) + this split's 32 c values
    float4v p00 = *(const float4v*)(xr + kgrp);
    float4v p01 = *(const float4v*)(xr + kgrp + 4);
    float4v p10 = *(const float4v*)(xr + 32 + kgrp);
    float4v p11 = *(const float4v*)(xr + 36 + kgrp);
    float4v xcv[8];
    #pragma unroll
    for (int q = 0; q < 8; ++q) xcv[q] = *(const float4v*)(xr + c0 + (q << 2));

    const short8v* wf = (const short8v*)wfrag;   // granules: [cc][nt*128+h*64+ln]

    float4v acc[4];
    #pragma unroll
    for (int nt = 0; nt < 4; ++nt)
        #pragma unroll
        for (int j = 0; j < 4; ++j) acc[nt][j] = 0.f;

    #pragma unroll 2
    for (int ci = 0; ci < 32; ++ci) {
        const short8v* base = wf + (((size_t)(c0 + ci)) << 9) + lane;
        short8v b0 = base[0];        // nt0 h0
        short8v b1 = base[64];       // nt0 h1
        short8v b2 = base[128];
        short8v b3 = base[192];
        short8v b4 = base[256];
        short8v b5 = base[320];
        short8v b6 = base[384];
        short8v b7 = base[448];

        float xc = xcv[ci >> 2][ci & 3];
        union { uint32_t u[4]; short8v s; } a0, a1;
        float4v q0 = p00 * xc, q1 = p01 * xc, q2 = p10 * xc, q3 = p11 * xc;
        a0.u[0] = cvtpk(q0[0], q0[1]); a0.u[1] = cvtpk(q0[2], q0[3]);
        a0.u[2] = cvtpk(q1[0], q1[1]); a0.u[3] = cvtpk(q1[2], q1[3]);
        a1.u[0] = cvtpk(q2[0], q2[1]); a1.u[1] = cvtpk(q2[2], q2[3]);
        a1.u[2] = cvtpk(q3[0], q3[1]); a1.u[3] = cvtpk(q3[2], q3[3]);

        acc[0] = __builtin_amdgcn_mfma_f32_16x16x32_bf16(a0.s, b0, acc[0], 0, 0, 0);
        acc[0] = __builtin_amdgcn_mfma_f32_16x16x32_bf16(a1.s, b1, acc[0], 0, 0, 0);
        acc[1] = __builtin_amdgcn_mfma_f32_16x16x32_bf16(a0.s, b2, acc[1], 0, 0, 0);
        acc[1] = __builtin_amdgcn_mfma_f32_16x16x32_bf16(a1.s, b3, acc[1], 0, 0, 0);
        acc[2] = __builtin_amdgcn_mfma_f32_16x16x32_bf16(a0.s, b4, acc[2], 0, 0, 0);
        acc[2] = __builtin_amdgcn_mfma_f32_16x16x32_bf16(a1.s, b5, acc[2], 0, 0, 0);
        acc[3] = __builtin_amdgcn_mfma_f32_16x16x32_bf16(a0.s, b6, acc[3], 0, 0, 0);
        acc[3] = __builtin_amdgcn_mfma_f32_16x16x32_bf16(a1.s, b7, acc[3], 0, 0, 0);
    }

    // epilogue: C/D layout col = lane&15 (n), row = (lane>>4)*4 + j
    float* gp = g + (size_t)split * ((size_t)S_DIM * 64);
    int crow0 = m0 + (wv << 4) + ((lane >> 4) << 2);
    int col0 = lane & 15;
    #pragma unroll
    for (int nt = 0; nt < 4; ++nt)
        #pragma unroll
        for (int j = 0; j < 4; ++j)
            gp[((size_t)(crow0 + j) << 6) + (nt << 4) + col0] = acc[nt][j];
}

// ---------------------------------------------------------------------------
// K4: out[s,n] = (sum_l w_l * (g0+g1)[s+l-7, n]) * rsq[s] + b[n]
// wave = 64 lanes (n), 16 consecutive s per wave, register row window.
// ---------------------------------------------------------------------------
__global__ __launch_bounds__(256) void k_final(const float* __restrict__ g,
                                               const float* __restrict__ rsq,
                                               const float* __restrict__ w,
                                               const float* __restrict__ conv_b,
                                               float* __restrict__ out) {
    int lane = threadIdx.x & 63, wv = threadIdx.x >> 6;
    int wid = blockIdx.x * 4 + wv;           // 0..1023
    int t0 = wid << 4;
    int bt0 = t0 & (T_DIM - 1);
    const float* g0 = g;
    const float* g1 = g + (size_t)S_DIM * 64;
    float r[30];
    #pragma unroll
    for (int i = 0; i < 30; ++i) {
        int tr = bt0 - 7 + i;
        r[i] = 0.f;
        if (0 <= tr && tr < T_DIM) {
            size_t gi = (((size_t)(t0 - 7 + i)) << 6) + lane;
            r[i] = g0[gi] + g1[gi];
        }
    }
    float bn = conv_b[lane];
    #pragma unroll
    for (int i = 0; i < 16; ++i) {
        float acc = 0.f;
        #pragma unroll
        for (int l = 0; l < 15; ++l) acc += w[l] * r[i + l];
        out[(((size_t)(t0 + i)) << 6) + lane] = acc * rsq[t0 + i] + bn;
    }
}

// ---------------------------------------------------------------------------
extern "C" void kernel_launch(void* const* d_in, const int* in_sizes, int n_in,
                              void* d_out, int out_size, void* d_ws, size_t ws_size,
                              hipStream_t stream) {
    const float* x      = (const float*)d_in[0];
    const float* w      = (const float*)d_in[1];
    const float* conv_w = (const float*)d_in[2];
    const float* conv_b = (const float*)d_in[3];
    float* out = (float*)d_out;

    char* ws = (char*)d_ws;
    unsigned short* wfrag = (unsigned short*)ws;                    //   524,288 B
    float* g              = (float*)(ws + 524288);                  // 8,388,608 B (2 K-split partials)
    float* P              = (float*)(ws + 524288 + 8388608);        // 1,048,576 B ([16][16384]; row 15 = rsq)
    float* rsq            = P + (size_t)15 * S_DIM;

    hipLaunchKernelGGL(k_convert, dim3(64),  dim3(256), 0, stream, conv_w, wfrag);
    hipLaunchKernelGGL(k_dotsP,   dim3(256), dim3(256), 0, stream, x, w, P);
    hipLaunchKernelGGL(k_gemm,    dim3(512), dim3(256), 0, stream, x, wfrag, g);
    hipLaunchKernelGGL(k_rsq,     dim3(64),  dim3(256), 0, stream, P, w, rsq);
    hipLaunchKernelGGL(k_final,   dim3(256), dim3(256), 0, stream, g, rsq, w, conv_b, out);
}